// Round 11
// baseline (327.326 us; speedup 1.0000x reference)
//
#include <hip/hip_runtime.h>
#include <math.h>

// GCDD fused v11: zero-LDS register sweep, HB=8, maskless interior,
// __launch_bounds__(256,5) occupancy floor, FUSED edge-column fixup.
// out = u + div( phi(G)*ux, phi(G)*uy ); 3x3 Sobel cross-correlations with zero
// padding at EVERY conv stage (intermediates forced to 0 outside the domain).
//
// R10 post-mortem: (a) VGPR crept to 112 -> 4 waves/SIMD ceiling ate the HB=8
// TLP; (b) separate fixup dispatch cost ~11us. v11: launch_bounds(256,5) caps
// VGPR ~96 (R9 proved this pipeline fits 96 without spill -> 5 waves/SIMD),
// and the 6-column fixup is fused as a post-loop tail (tid<96 per block,
// loads L1-hot, no second dispatch). Spill canary: WRITE_SIZE must stay 49152.
//
// Pipeline at iter T (band-row k <-> abs gy = gy0 + k - 3):
//   C(T):  consume pend (u row T) -> Du/Su/ucen[T%3]
//          Du[c]=u[c+3]-u[c+1], Su[c]=u[c+1]+2u[c+2]+u[c+3]
//   L'(T): load u band-row T+1 -> pend (abs gy0+T-2)
//   UX(T): ux row T-1 -> xw/yw[(T-1)%3]: ux=Du(t)+2Du(m)+Du(b), uy=Su(b)-Su(t)
//   PQ(T): P,Q row T-2 -> pre-reduced dP/eQ[(T-2)%3]
//   OUT(T): out row T-3 = u + (dP[r-1]+2dP[r]+dP[r+1]) + (eQ[r+1]-eQ[r-1])
// Horizontal masks dropped: clamped-load garbage propagates <=3 cols; out cols
// {0,1,2,W-3,W-2,W-1} are rewritten by the fused masked-cascade tail.
// Block: 256 threads = 2 bands x 128 strips (4 cols each). Grid y = H/(2*HB).

#define HB   8
#define NROW (HB + 6)   // 14 active pipeline iterations
#define NT   256

typedef float f4v __attribute__((ext_vector_type(4)));

#define STEP(TT, S0, S1, S2) do {                                              \
    const int Tt = (TT);                                                       \
    const float ur0 = ucen[S0][0], ur1 = ucen[S0][1],                          \
                ur2 = ucen[S0][2], ur3 = ucen[S0][3];                          \
    if (Tt < NROW) {                                                           \
        /* ---- C(Tt): consume pend (u row Tt) -> Du/Su/ucen[S0] ---- */       \
        float* du = Du[S0]; float* su = Su[S0];                                \
        _Pragma("unroll") for (int c = 0; c < 8; ++c) {                        \
            du[c] = pend[c+3] - pend[c+1];                                     \
            su[c] = pend[c+1] + 2.f*pend[c+2] + pend[c+3];                     \
        }                                                                      \
        ucen[S0][0] = pend[4]; ucen[S0][1] = pend[5];                          \
        ucen[S0][2] = pend[6]; ucen[S0][3] = pend[7];                          \
    }                                                                          \
    if (Tt + 1 < NROW) {                                                       \
        /* ---- L'(Tt): load u band-row Tt+1 -> pend (abs gy=gy0+Tt-2) ---- */ \
        const int gy = gy0 + Tt - 2;                                           \
        if ((unsigned)gy < (unsigned)H) {                                      \
            const float* row = uc + (long)gy * W;                              \
            *(float4*)&pend[0] = *(const float4*)(row + ca);                   \
            *(float4*)&pend[4] = *(const float4*)(row + c0);                   \
            *(float4*)&pend[8] = *(const float4*)(row + cc);                   \
        } else {                                                               \
            _Pragma("unroll") for (int i = 0; i < 12; ++i) pend[i] = 0.f;      \
        }                                                                      \
    }                                                                          \
    if (Tt >= 2 && Tt < NROW) {                                                \
        /* ---- UX(Tt): ux/uy band-row Tt-1 (abs gy=gy0+Tt-4) -> slot S2 ---- */ \
        float* xr = xw[S2]; float* yr = yw[S2];                                \
        const int gy = gy0 + Tt - 4;                                           \
        if ((unsigned)gy < (unsigned)H) {                                      \
            _Pragma("unroll") for (int c = 0; c < 8; ++c) {                    \
                xr[c] = Du[S1][c] + 2.f*Du[S2][c] + Du[S0][c];                 \
                yr[c] = Su[S0][c] - Su[S1][c];                                 \
            }                                                                  \
        } else {                                                               \
            _Pragma("unroll") for (int c = 0; c < 8; ++c) { xr[c]=0.f; yr[c]=0.f; } \
        }                                                                      \
    }                                                                          \
    if (Tt >= 4 && Tt < NROW) {                                                \
        /* ---- PQ(Tt): P band-row Tt-2 (abs gy=gy0+Tt-5) -> dP/eQ[S1] ---- */ \
        float* dp = dP[S1]; float* eq = eQ[S1];                                \
        const int gy = gy0 + Tt - 5;                                           \
        if ((unsigned)gy < (unsigned)H) {                                      \
            const float* xt = xw[S0];  /* ux row Tt-3 */                       \
            const float* xm = xw[S1];  /* ux row Tt-2 */                       \
            const float* xb = xw[S2];  /* ux row Tt-1 */                       \
            const float* yt = yw[S0];                                          \
            const float* ym = yw[S1];                                          \
            const float* yb = yw[S2];                                          \
            float P[6], Q[6];                                                  \
            _Pragma("unroll") for (int c = 0; c < 6; ++c) {                    \
                const float xc = xm[c+1], yc = ym[c+1];                        \
                const float uxx = (xt[c+2]-xt[c]) + 2.f*(xm[c+2]-xm[c])        \
                                + (xb[c+2]-xb[c]);                             \
                const float uxy = (xb[c] + 2.f*xb[c+1] + xb[c+2])              \
                                - (xt[c] + 2.f*xt[c+1] + xt[c+2]);             \
                const float uyy = (yb[c] + 2.f*yb[c+1] + yb[c+2])              \
                                - (yt[c] + 2.f*yt[c+1] + yt[c+2]);             \
                const float den = 1.f + xc*xc + yc*yc;                         \
                const float Gv = (uxx*uyy - uxy*uxy)                           \
                               * __builtin_amdgcn_rcpf(den*den + 1e-6f);       \
                const float phi = __expf(-fabsf(Gv));                          \
                P[c] = phi * xc;                                               \
                Q[c] = phi * yc;                                               \
            }                                                                  \
            dp[0] = P[2]-P[0]; dp[1] = P[3]-P[1];                              \
            dp[2] = P[4]-P[2]; dp[3] = P[5]-P[3];                              \
            eq[0] = Q[0]+2.f*Q[1]+Q[2]; eq[1] = Q[1]+2.f*Q[2]+Q[3];            \
            eq[2] = Q[2]+2.f*Q[3]+Q[4]; eq[3] = Q[3]+2.f*Q[4]+Q[5];            \
        } else {                                                               \
            _Pragma("unroll") for (int c = 0; c < 4; ++c) { dp[c]=0.f; eq[c]=0.f; } \
        }                                                                      \
    }                                                                          \
    if (Tt >= 6 && Tt < NROW) {                                                \
        /* ---- OUT(Tt): out band-row Tt-3, abs gy = gy0+Tt-6 (in-domain) ---- */ \
        f4v o;                                                                 \
        o.x = ur0 + (dP[S2][0] + 2.f*dP[S0][0] + dP[S1][0])                    \
                  + (eQ[S1][0] - eQ[S2][0]);                                   \
        o.y = ur1 + (dP[S2][1] + 2.f*dP[S0][1] + dP[S1][1])                    \
                  + (eQ[S1][1] - eQ[S2][1]);                                   \
        o.z = ur2 + (dP[S2][2] + 2.f*dP[S0][2] + dP[S1][2])                    \
                  + (eQ[S1][2] - eQ[S2][2]);                                   \
        o.w = ur3 + (dP[S2][3] + 2.f*dP[S0][3] + dP[S1][3])                    \
                  + (eQ[S1][3] - eQ[S2][3]);                                   \
        __builtin_nontemporal_store(o, (f4v*)(oc + (long)(gy0 + Tt - 6) * W + c0)); \
    }                                                                          \
} while (0)

__global__ __launch_bounds__(NT, 5) void gcdd_sweep(
    const float* __restrict__ u, float* __restrict__ out, int H, int W)
{
    const int tid   = threadIdx.x;
    const int strip = tid & 127;          // 128 strips x 4 cols = W = 512
    const int band  = tid >> 7;           // 2 bands per block (wave-uniform)
    const int c0    = strip * 4;
    const int by0   = blockIdx.y * (2 * HB);
    const int gy0   = by0 + band * HB;
    const long chan = blockIdx.z;
    const float* __restrict__ uc = u + chan * (long)H * W;
    float* __restrict__ oc = out + chan * (long)H * W;

    // Clamped side-load cols: edge strips read garbage there; the affected
    // out cols {0,1,2, W-3,W-2,W-1} are rewritten by the fused fixup tail.
    const int ca = (c0 - 4 < 0) ? 0 : (c0 - 4);
    const int cc = (c0 + 4 > W - 4) ? (W - 4) : (c0 + 4);

    {
        float pend[12];
        float Du[3][8], Su[3][8];
        float ucen[3][4] = {};
        float xw[3][8], yw[3][8];
        float dP[3][4], eQ[3][4];

        // ---- Prologue: load band-row 0 (abs gy = gy0-3) into pend ----
        {
            const int gy = gy0 - 3;
            if ((unsigned)gy < (unsigned)H) {
                const float* row = uc + (long)gy * W;
                *(float4*)&pend[0] = *(const float4*)(row + ca);
                *(float4*)&pend[4] = *(const float4*)(row + c0);
                *(float4*)&pend[8] = *(const float4*)(row + cc);
            } else {
                #pragma unroll
                for (int i = 0; i < 12; ++i) pend[i] = 0.f;
            }
        }

        // 15 iterations (14 active), 3x-unrolled: all slot indices literal.
        for (int t = 0; t < NROW + 1; t += 3) {
            STEP(t + 0, 0, 1, 2);
            STEP(t + 1, 1, 2, 0);
            STEP(t + 2, 2, 0, 1);
        }
    }

    // ---- Fused fixup: rewrite out cols {0,1,2, W-3,W-2,W-1} of this block's
    // 16 rows with the fully-masked per-pixel cascade. syncthreads drains the
    // main loop's (garbage) stores first; loads here are L1/L2-hot.
    __syncthreads();
    if (tid < 6 * 2 * HB) {
        const int r  = tid / 6;
        const int j  = tid - 6 * r;
        const int gy = by0 + r;
        const int gx = (j < 3) ? j : (W - 6 + j);

        float uv[7][7];
        #pragma unroll
        for (int rr = 0; rr < 7; ++rr) {
            const int ry = gy - 3 + rr;
            const bool ri = (unsigned)ry < (unsigned)H;
            const int ryc = ri ? ry : 0;
            #pragma unroll
            for (int c = 0; c < 7; ++c) {
                const int cx = gx - 3 + c;
                const bool ci = (unsigned)cx < (unsigned)W;
                const int cxc = ci ? cx : 0;
                const float v = uc[(long)ryc * W + cxc];
                uv[rr][c] = (ri & ci) ? v : 0.f;
            }
        }
        float ux[5][5], uy[5][5];
        #pragma unroll
        for (int rr = 0; rr < 5; ++rr) {
            const bool ri = (unsigned)(gy - 2 + rr) < (unsigned)H;
            #pragma unroll
            for (int c = 0; c < 5; ++c) {
                const bool in = ri & ((unsigned)(gx - 2 + c) < (unsigned)W);
                const float A = uv[rr][c],   B = uv[rr][c+1],   C = uv[rr][c+2];
                const float D = uv[rr+1][c],                    E = uv[rr+1][c+2];
                const float F = uv[rr+2][c], G = uv[rr+2][c+1], Hh = uv[rr+2][c+2];
                const float x = (C - A) + 2.f*(E - D) + (Hh - F);
                const float y = (F + 2.f*G + Hh) - (A + 2.f*B + C);
                ux[rr][c] = in ? x : 0.f;
                uy[rr][c] = in ? y : 0.f;
            }
        }
        float P[3][3], Q[3][3];
        #pragma unroll
        for (int rr = 0; rr < 3; ++rr) {
            const bool ri = (unsigned)(gy - 1 + rr) < (unsigned)H;
            #pragma unroll
            for (int c = 0; c < 3; ++c) {
                const bool in = ri & ((unsigned)(gx - 1 + c) < (unsigned)W);
                const float xc = ux[rr+1][c+1], yc = uy[rr+1][c+1];
                const float uxx = (ux[rr][c+2]-ux[rr][c]) + 2.f*(ux[rr+1][c+2]-ux[rr+1][c])
                                + (ux[rr+2][c+2]-ux[rr+2][c]);
                const float uxy = (ux[rr+2][c] + 2.f*ux[rr+2][c+1] + ux[rr+2][c+2])
                                - (ux[rr][c]   + 2.f*ux[rr][c+1]   + ux[rr][c+2]);
                const float uyy = (uy[rr+2][c] + 2.f*uy[rr+2][c+1] + uy[rr+2][c+2])
                                - (uy[rr][c]   + 2.f*uy[rr][c+1]   + uy[rr][c+2]);
                const float den = 1.f + xc*xc + yc*yc;
                const float Gv = (uxx*uyy - uxy*uxy)
                               * __builtin_amdgcn_rcpf(den*den + 1e-6f);
                const float phi = __expf(-fabsf(Gv));
                P[rr][c] = in ? phi * xc : 0.f;
                Q[rr][c] = in ? phi * yc : 0.f;
            }
        }
        const float divx = (P[0][2]-P[0][0]) + 2.f*(P[1][2]-P[1][0]) + (P[2][2]-P[2][0]);
        const float divy = (Q[2][0] + 2.f*Q[2][1] + Q[2][2])
                         - (Q[0][0] + 2.f*Q[0][1] + Q[0][2]);
        oc[(long)gy * W + gx] = uv[3][3] + divx + divy;
    }
}

extern "C" void kernel_launch(void* const* d_in, const int* in_sizes, int n_in,
                              void* d_out, int out_size, void* d_ws, size_t ws_size,
                              hipStream_t stream) {
    const float* u = (const float*)d_in[0];
    float* out = (float*)d_out;

    const int H = 512, W = 512;
    const int channels = in_sizes[0] / (H * W);  // B*C = 48

    dim3 grid(1, H / (2 * HB), channels);        // 1 x 32 x 48 = 1536 blocks
    gcdd_sweep<<<grid, dim3(NT), 0, stream>>>(u, out, H, W);
}

// Round 12
// 50.851 us; speedup vs baseline: 6.4370x; 6.4370x over previous
//
#include <hip/hip_runtime.h>
#include <math.h>

// GCDD fused v12 = R7 (best, 48.3us) + HB=8 (2x TLP) + proven PQ-mask removal.
// out = u + div( phi(G)*ux, phi(G)*uy ); 3x3 Sobel cross-correlations with zero
// padding at EVERY conv stage (intermediates forced to 0 outside the domain).
//
// Rationale (R11 post-mortem): busy-time is ~30us in every variant; the wall
// gap is stall. TLP is grid-limited: total threads = 512*512*48/(4*HB), so
// HB=8 doubles waves/SIMD to 6 at VGPR<=85. R7's load placement is kept
// EXACTLY (both prefetch restructures regressed); PQ cndmasks removed (R9-R11
// proved ux/uy==0 at invalid cols + finite phi => P,Q inherit zeros).
// NO launch_bounds floor (R11: bounding below live state -> 677MB spills).
// NO fused fixup tail (R11: register-heavy tail shares the allocator budget).
//
// Pipeline at iter T (band-row k <-> abs gy = gy0 + k - 3):
//   L(T):  load u band-row T -> uw[T%3], ucen[T%3]
//   UX(T): ux/uy band-row T-1 -> xw/yw[(T-1)%3]   (masked at invalid cols)
//   PQ(T): P,Q band-row T-2 -> pre-reduced dP/eQ[(T-2)%3]:
//          dP=P[c+1]-P[c-1], eQ=Q[c-1]+2Q[c]+Q[c+1]
//   OUT(T): out band-row T-3 = u + (dP[r-1]+2dP[r]+dP[r+1]) + (eQ[r+1]-eQ[r-1])
// Block: 256 threads = 2 bands x 128 strips (4 cols each). Grid y = H/(2*HB).

#define HB   8
#define NROW (HB + 6)   // 14 active pipeline iterations
#define NT   256

#define STEP(TT, S0, S1, S2) do {                                              \
    const int Tt = (TT);                                                       \
    /* residual u (band-row Tt-3, slot S0) BEFORE L overwrites it */           \
    const float ur0 = ucen[S0][0], ur1 = ucen[S0][1],                          \
                ur2 = ucen[S0][2], ur3 = ucen[S0][3];                          \
    if (Tt < NROW) {                                                           \
        /* ---- L(Tt): u band-row Tt, abs gy = gy0+Tt-3 ---- */                \
        const int gy = gy0 + Tt - 3;                                           \
        float* w = uw[S0];                                                     \
        if ((unsigned)gy < (unsigned)H) {                                      \
            const float* row = uc + (long)gy * W;                              \
            const float4 va = *(const float4*)(row + ca);                      \
            const float4 vb = *(const float4*)(row + c0);                      \
            const float4 vc = *(const float4*)(row + cc);                      \
            w[0] = inb0  ? va.x : 0.f;  w[1]  = inb1  ? va.y : 0.f;            \
            w[2] = inb2  ? va.z : 0.f;  w[3]  = inb3  ? va.w : 0.f;            \
            w[4] = vb.x;                w[5]  = vb.y;                          \
            w[6] = vb.z;                w[7]  = vb.w;                          \
            w[8] = inb8  ? vc.x : 0.f;  w[9]  = inb9  ? vc.y : 0.f;            \
            w[10] = inb10 ? vc.z : 0.f; w[11] = inb11 ? vc.w : 0.f;            \
        } else {                                                               \
            _Pragma("unroll") for (int i = 0; i < 12; ++i) w[i] = 0.f;         \
        }                                                                      \
        ucen[S0][0] = w[4]; ucen[S0][1] = w[5];                                \
        ucen[S0][2] = w[6]; ucen[S0][3] = w[7];                                \
    }                                                                          \
    if (Tt >= 2 && Tt < NROW) {                                                \
        /* ---- UX(Tt): ux/uy band-row Tt-1, abs gy = gy0+Tt-4 ---- */         \
        float* xr = xw[S2]; float* yr = yw[S2];                                \
        const int gy = gy0 + Tt - 4;                                           \
        if ((unsigned)gy < (unsigned)H) {                                      \
            const float* a = uw[S1];   /* row Tt-2 */                          \
            const float* m = uw[S2];   /* row Tt-1 */                          \
            const float* b = uw[S0];   /* row Tt   */                          \
            _Pragma("unroll") for (int c = 0; c < 8; ++c) {                    \
                const float A = a[c+1], B = a[c+2], C = a[c+3];                \
                const float D = m[c+1],             E = m[c+3];                \
                const float F = b[c+1], Gg = b[c+2], Hh = b[c+3];              \
                const float x = (C - A) + 2.f*(E - D) + (Hh - F);              \
                const float y = (F + 2.f*Gg + Hh) - (A + 2.f*B + C);           \
                xr[c] = mU[c+2] ? x : 0.f;                                     \
                yr[c] = mU[c+2] ? y : 0.f;                                     \
            }                                                                  \
        } else {                                                               \
            _Pragma("unroll") for (int c = 0; c < 8; ++c) { xr[c]=0.f; yr[c]=0.f; } \
        }                                                                      \
    }                                                                          \
    if (Tt >= 4 && Tt < NROW) {                                                \
        /* ---- PQ(Tt): P band-row Tt-2, abs gy = gy0+Tt-5 ---- */             \
        float* dp = dP[S1]; float* eq = eQ[S1];                                \
        const int gy = gy0 + Tt - 5;                                           \
        if ((unsigned)gy < (unsigned)H) {                                      \
            const float* xt = xw[S0];  /* ux row Tt-3 */                       \
            const float* xm = xw[S1];  /* ux row Tt-2 */                       \
            const float* xb = xw[S2];  /* ux row Tt-1 */                       \
            const float* yt = yw[S0];                                          \
            const float* ym = yw[S1];                                          \
            const float* yb = yw[S2];                                          \
            float P[6], Q[6];                                                  \
            _Pragma("unroll") for (int c = 0; c < 6; ++c) {                    \
                const float xc = xm[c+1], yc = ym[c+1];                        \
                const float uxx = (xt[c+2]-xt[c]) + 2.f*(xm[c+2]-xm[c])        \
                                + (xb[c+2]-xb[c]);                             \
                const float uxy = (xb[c] + 2.f*xb[c+1] + xb[c+2])              \
                                - (xt[c] + 2.f*xt[c+1] + xt[c+2]);             \
                const float uyy = (yb[c] + 2.f*yb[c+1] + yb[c+2])              \
                                - (yt[c] + 2.f*yt[c+1] + yt[c+2]);             \
                const float den = 1.f + xc*xc + yc*yc;                         \
                const float Gv = (uxx*uyy - uxy*uxy)                           \
                               * __builtin_amdgcn_rcpf(den*den + 1e-6f);       \
                const float phi = __expf(-fabsf(Gv));                          \
                /* xc,yc already 0 at invalid cols; phi finite -> P,Q = 0 */   \
                P[c] = phi * xc;                                               \
                Q[c] = phi * yc;                                               \
            }                                                                  \
            dp[0] = P[2]-P[0]; dp[1] = P[3]-P[1];                              \
            dp[2] = P[4]-P[2]; dp[3] = P[5]-P[3];                              \
            eq[0] = Q[0]+2.f*Q[1]+Q[2]; eq[1] = Q[1]+2.f*Q[2]+Q[3];            \
            eq[2] = Q[2]+2.f*Q[3]+Q[4]; eq[3] = Q[3]+2.f*Q[4]+Q[5];            \
        } else {                                                               \
            _Pragma("unroll") for (int c = 0; c < 4; ++c) { dp[c]=0.f; eq[c]=0.f; } \
        }                                                                      \
    }                                                                          \
    if (Tt >= 6 && Tt < NROW) {                                                \
        /* ---- OUT(Tt): out band-row Tt-3, abs gy = gy0+Tt-6 (in-domain) ---- */ \
        /* P rows: gy-1 -> S2 (w1), gy -> S0 (w2), gy+1 -> S1 (w1) */          \
        const float o0 = ur0 + (dP[S2][0] + 2.f*dP[S0][0] + dP[S1][0])         \
                             + (eQ[S1][0] - eQ[S2][0]);                        \
        const float o1 = ur1 + (dP[S2][1] + 2.f*dP[S0][1] + dP[S1][1])         \
                             + (eQ[S1][1] - eQ[S2][1]);                        \
        const float o2 = ur2 + (dP[S2][2] + 2.f*dP[S0][2] + dP[S1][2])         \
                             + (eQ[S1][2] - eQ[S2][2]);                        \
        const float o3 = ur3 + (dP[S2][3] + 2.f*dP[S0][3] + dP[S1][3])         \
                             + (eQ[S1][3] - eQ[S2][3]);                        \
        *(float4*)(oc + (long)(gy0 + Tt - 6) * W + c0) =                       \
            make_float4(o0, o1, o2, o3);                                       \
    }                                                                          \
} while (0)

__global__ __launch_bounds__(NT) void gcdd_sweep(
    const float* __restrict__ u, float* __restrict__ out, int H, int W)
{
    const int tid   = threadIdx.x;
    const int strip = tid & 127;          // 128 strips x 4 cols = W = 512
    const int band  = tid >> 7;           // 2 bands per block (wave-uniform)
    const int c0    = strip * 4;
    const int gy0   = (blockIdx.y * 2 + band) * HB;
    const long chan = blockIdx.z;
    const float* __restrict__ uc = u + chan * (long)H * W;
    float* __restrict__ oc = out + chan * (long)H * W;

    // Clamped load-base cols (keeps addresses in-bounds; clamped-in values are
    // masked to zero below, implementing the zero-padding of the first conv).
    const int ca = (c0 - 4 < 0) ? 0 : (c0 - 4);
    const int cc = (c0 + 4 > W - 4) ? (W - 4) : (c0 + 4);

    // uw[i] holds u col c0-4+i; validity masks (only edge strips have false).
    bool mU[12];
    #pragma unroll
    for (int i = 0; i < 12; ++i)
        mU[i] = (unsigned)(c0 - 4 + i) < (unsigned)W;
    const bool inb0 = mU[0], inb1 = mU[1], inb2 = mU[2], inb3 = mU[3];
    const bool inb8 = mU[8], inb9 = mU[9], inb10 = mU[10], inb11 = mU[11];

    float uw[3][12];
    float ucen[3][4] = {};
    float xw[3][8], yw[3][8];
    float dP[3][4], eQ[3][4];

    // 15 iterations (14 active), 3x-unrolled: all slot indices literal.
    for (int t = 0; t < NROW + 1; t += 3) {
        STEP(t + 0, 0, 1, 2);
        STEP(t + 1, 1, 2, 0);
        STEP(t + 2, 2, 0, 1);
    }
}

extern "C" void kernel_launch(void* const* d_in, const int* in_sizes, int n_in,
                              void* d_out, int out_size, void* d_ws, size_t ws_size,
                              hipStream_t stream) {
    const float* u = (const float*)d_in[0];
    float* out = (float*)d_out;

    const int H = 512, W = 512;
    const int channels = in_sizes[0] / (H * W);  // B*C = 48

    dim3 grid(1, H / (2 * HB), channels);        // 1 x 32 x 48 = 1536 blocks
    dim3 block(NT);
    gcdd_sweep<<<grid, block, 0, stream>>>(u, out, H, W);
}